// Round 6
// baseline (253.315 us; speedup 1.0000x reference)
//
#include <hip/hip_runtime.h>
#include <hip/hip_fp16.h>

#define INCH   128
#define HEADS1 8
#define HID1   16
#define C1     128   // HEADS1*HID1
#define C2     64
#define NEG_SLOPE 0.2f
#define SB     256   // scan blocks / threads

using f16x8 = __attribute__((ext_vector_type(8))) _Float16;
using f32x4 = __attribute__((ext_vector_type(4))) float;

__device__ __forceinline__ float lrelu(float v) { return v >= 0.f ? v : NEG_SLOPE * v; }
// byte-offset swizzle within a 256B LDS row (rows are 128 fp16)
__device__ __forceinline__ int swzA(int row, int byteInRow) {
  return (row << 8) | (byteInRow ^ ((row & 15) << 4));
}

// ---------------- prep: fp32 -> fp16 conversions ----------------

__global__ void cvt_fp16(const float* __restrict__ in, __half* __restrict__ o, int total8) {
  int i = blockIdx.x * blockDim.x + threadIdx.x;
  if (i >= total8) return;
  const float4* p = (const float4*)in + (size_t)i * 2;
  float4 v0 = p[0], v1 = p[1];
  __half2 ha = __floats2half2_rn(v0.x, v0.y);
  __half2 hb = __floats2half2_rn(v0.z, v0.w);
  __half2 hc = __floats2half2_rn(v1.x, v1.y);
  __half2 hd = __floats2half2_rn(v1.z, v1.w);
  uint4 w = { *(unsigned*)&ha, *(unsigned*)&hb, *(unsigned*)&hc, *(unsigned*)&hd };
  ((uint4*)o)[i] = w;
}

// W[K][Ncol] (row-major fp32) -> Wt[Ncol][K] (fp16)
__global__ void transpose_fp16(const float* __restrict__ W, __half* __restrict__ Wt,
                               int K, int Ncol) {
  int id = blockIdx.x * blockDim.x + threadIdx.x;
  if (id >= K * Ncol) return;
  int col = id / K, k = id % K;
  Wt[id] = __float2half(W[k * Ncol + col]);
}

// ---------------- CSR build (by destination) ----------------

__global__ void hist_kernel(const int* __restrict__ dst, int* __restrict__ deg, int E) {
  int e = blockIdx.x * blockDim.x + threadIdx.x;
  if (e < E) atomicAdd(&deg[dst[e]], 1);
}

__global__ void scan1_kernel(const int* __restrict__ deg, int* __restrict__ partial, int N) {
  __shared__ int sh[SB];
  const int b = blockIdx.x, t = threadIdx.x;
  const int chunk = (N + SB - 1) / SB;
  const int lo = b * chunk, hi = min(lo + chunk, N);
  int s = 0;
  for (int i = lo + t; i < hi; i += SB) s += deg[i];
  sh[t] = s;
  __syncthreads();
  for (int off = SB / 2; off; off >>= 1) {
    if (t < off) sh[t] += sh[t + off];
    __syncthreads();
  }
  if (t == 0) partial[b] = sh[0];
}

__global__ void scan2_kernel(int* __restrict__ partial) {
  __shared__ int sh[SB];
  const int t = threadIdx.x;
  int v = partial[t];
  sh[t] = v;
  __syncthreads();
  for (int off = 1; off < SB; off <<= 1) {
    int u = (t >= off) ? sh[t - off] : 0;
    __syncthreads();
    sh[t] += u;
    __syncthreads();
  }
  partial[t] = sh[t] - v;
}

__global__ void scan3_kernel(const int* __restrict__ deg, const int* __restrict__ partial,
                             int* __restrict__ row_start, int N) {
  __shared__ int sh[SB];
  const int b = blockIdx.x, t = threadIdx.x;
  const int chunk = (N + SB - 1) / SB;
  const int lo = b * chunk, hi = min(lo + chunk, N);
  int run = partial[b];
  for (int base = lo; base < hi; base += SB) {
    int i = base + t;
    int v = (i < hi) ? deg[i] : 0;
    sh[t] = v;
    __syncthreads();
    for (int off = 1; off < SB; off <<= 1) {
      int u = (t >= off) ? sh[t - off] : 0;
      __syncthreads();
      sh[t] += u;
      __syncthreads();
    }
    if (i < hi) row_start[i] = run + sh[t] - v;
    run += sh[SB - 1];
    __syncthreads();
  }
  if (b == SB - 1 && t == 0) row_start[N] = run;
}

__global__ void fill_kernel(const int* __restrict__ src, const int* __restrict__ dst,
                            const int* __restrict__ row_start, int* __restrict__ cursor,
                            int* __restrict__ src_sorted, int E) {
  int e = blockIdx.x * blockDim.x + threadIdx.x;
  if (e >= E) return;
  int d = dst[e];
  int slot = row_start[d] + atomicAdd(&cursor[d], 1);
  src_sorted[slot] = src[e];
}

// ---------------- MFMA GEMMs ----------------
// gemm1: [M x 128] x [128 x 128]; 256 thr = 4 waves; block does 64 rows x 128 cols.
__global__ __launch_bounds__(256) void gemm1_mfma(
    const __half* __restrict__ xh, const __half* __restrict__ W1t,
    const float* __restrict__ a_src, const float* __restrict__ a_dst,
    __half* __restrict__ h1, float* __restrict__ s1, float* __restrict__ d1, int M) {
  __shared__ unsigned char As[16384];   // 64 x 128 fp16, swizzled
  __shared__ unsigned char Bs[32768];   // 128 x 128 fp16 (col-major W1), swizzled
  const int t = threadIdx.x;
  const int m0 = blockIdx.x * 64;
  for (int c = t; c < 1024; c += 256) {
    int row = c >> 4, seg = c & 15;
    int gr = m0 + row;
    uint4 v = make_uint4(0, 0, 0, 0);
    if (gr < M) v = ((const uint4*)xh)[(size_t)gr * 16 + seg];
    *(uint4*)(As + swzA(row, seg << 4)) = v;
  }
  for (int c = t; c < 2048; c += 256) {
    int row = c >> 4, seg = c & 15;
    uint4 v = ((const uint4*)W1t)[(row << 4) + seg];
    *(uint4*)(Bs + swzA(row, seg << 4)) = v;
  }
  __syncthreads();
  const int l = t & 63, wid = t >> 6;
  const int c16 = l & 15;                 // col / row-low nibble
  const int kOff = (l >> 4) << 4;         // byte offset of this lane's 8 k-elems
  const int rA = (wid << 4) | c16;
  f16x8 a[4];
#pragma unroll
  for (int kb = 0; kb < 4; ++kb)
    a[kb] = *(const f16x8*)(As + swzA(rA, (kb << 6) + kOff));
#pragma unroll
  for (int ct = 0; ct < 8; ++ct) {        // ct == head (HID1 == 16)
    const int rB = (ct << 4) | c16;
    f32x4 acc = {0.f, 0.f, 0.f, 0.f};
#pragma unroll
    for (int kb = 0; kb < 4; ++kb) {
      f16x8 b = *(const f16x8*)(Bs + swzA(rB, (kb << 6) + kOff));
      acc = __builtin_amdgcn_mfma_f32_16x16x32_f16(a[kb], b, acc, 0, 0, 0);
    }
    const int colg = (ct << 4) + c16;
    const float asv = a_src[colg], adv = a_dst[colg];
#pragma unroll
    for (int i = 0; i < 4; ++i) {
      const int n = m0 + (wid << 4) + ((l >> 4) << 2) + i;
      float v = acc[i];
      float sv = v * asv, dv = v * adv;
      sv += __shfl_xor(sv, 1); sv += __shfl_xor(sv, 2);
      sv += __shfl_xor(sv, 4); sv += __shfl_xor(sv, 8);
      dv += __shfl_xor(dv, 1); dv += __shfl_xor(dv, 2);
      dv += __shfl_xor(dv, 4); dv += __shfl_xor(dv, 8);
      if (n < M) {
        h1[(size_t)n * C1 + colg] = __float2half(v);
        if (c16 == 0) { s1[n * HEADS1 + ct] = sv; d1[n * HEADS1 + ct] = dv; }
      }
    }
  }
}

// gemm2: [M x 128] x [128 x 64]
__global__ __launch_bounds__(256) void gemm2_mfma(
    const __half* __restrict__ x2h, const __half* __restrict__ W2t,
    const float* __restrict__ a_src, const float* __restrict__ a_dst,
    __half* __restrict__ h2, float* __restrict__ s2, float* __restrict__ d2, int M) {
  __shared__ unsigned char As[16384];   // 64 x 128 fp16
  __shared__ unsigned char Bs[16384];   // 64 x 128 fp16 (col-major W2)
  const int t = threadIdx.x;
  const int m0 = blockIdx.x * 64;
  for (int c = t; c < 1024; c += 256) {
    int row = c >> 4, seg = c & 15;
    int gr = m0 + row;
    uint4 v = make_uint4(0, 0, 0, 0);
    if (gr < M) v = ((const uint4*)x2h)[(size_t)gr * 16 + seg];
    *(uint4*)(As + swzA(row, seg << 4)) = v;
  }
  for (int c = t; c < 1024; c += 256) {
    int row = c >> 4, seg = c & 15;
    uint4 v = ((const uint4*)W2t)[(row << 4) + seg];
    *(uint4*)(Bs + swzA(row, seg << 4)) = v;
  }
  __syncthreads();
  const int l = t & 63, wid = t >> 6;
  const int c16 = l & 15;
  const int kOff = (l >> 4) << 4;
  const int rA = (wid << 4) | c16;
  f16x8 a[4];
#pragma unroll
  for (int kb = 0; kb < 4; ++kb)
    a[kb] = *(const f16x8*)(As + swzA(rA, (kb << 6) + kOff));
  float svp[4] = {0.f, 0.f, 0.f, 0.f};
  float dvp[4] = {0.f, 0.f, 0.f, 0.f};
#pragma unroll
  for (int ct = 0; ct < 4; ++ct) {
    const int rB = (ct << 4) | c16;
    f32x4 acc = {0.f, 0.f, 0.f, 0.f};
#pragma unroll
    for (int kb = 0; kb < 4; ++kb) {
      f16x8 b = *(const f16x8*)(Bs + swzA(rB, (kb << 6) + kOff));
      acc = __builtin_amdgcn_mfma_f32_16x16x32_f16(a[kb], b, acc, 0, 0, 0);
    }
    const int colg = (ct << 4) + c16;
    const float asv = a_src[colg], adv = a_dst[colg];
#pragma unroll
    for (int i = 0; i < 4; ++i) {
      const int n = m0 + (wid << 4) + ((l >> 4) << 2) + i;
      float v = acc[i];
      svp[i] += v * asv;
      dvp[i] += v * adv;
      if (n < M) h2[(size_t)n * C2 + colg] = __float2half(v);
    }
  }
#pragma unroll
  for (int i = 0; i < 4; ++i) {
    float sv = svp[i], dv = dvp[i];
    sv += __shfl_xor(sv, 1); sv += __shfl_xor(sv, 2);
    sv += __shfl_xor(sv, 4); sv += __shfl_xor(sv, 8);
    dv += __shfl_xor(dv, 1); dv += __shfl_xor(dv, 2);
    dv += __shfl_xor(dv, 4); dv += __shfl_xor(dv, 8);
    const int n = m0 + (wid << 4) + ((l >> 4) << 2) + i;
    if (c16 == 0 && n < M) { s2[n] = sv; d2[n] = dv; }
  }
}

// ---------------- Fused online-softmax aggregation ----------------
// One 64-lane wave per destination node; lane covers channels (2*lane, 2*lane+1);
// head = lane>>3. Running {m, z, acc} per lane; rescale on new max.

__global__ __launch_bounds__(256) void agg1_fused(
    const int* __restrict__ row_start, const int* __restrict__ src_sorted,
    const float* __restrict__ s1, const float* __restrict__ d1,
    const __half* __restrict__ h1, const float* __restrict__ b1,
    __half* __restrict__ x2h, int N) {
  const int n = blockIdx.x * 4 + (threadIdx.x >> 6);
  if (n >= N) return;
  const int lane = threadIdx.x & 63;
  const int h = lane >> 3;
  const int c0 = lane << 1;
  const float dv = d1[n * HEADS1 + h];
  const int lo = row_start[n], hi = row_start[n + 1];
  float m = -INFINITY, z = 0.f, ax = 0.f, ay = 0.f;
  int i = lo;
  for (; i + 2 <= hi; i += 2) {
    const int sA = src_sorted[i], sB = src_sorted[i + 1];
    const float svA = s1[sA * HEADS1 + h];
    const float svB = s1[sB * HEADS1 + h];
    const __half2 hA = *(const __half2*)&h1[(size_t)sA * C1 + c0];
    const __half2 hB = *(const __half2*)&h1[(size_t)sB * C1 + c0];
    float vA = lrelu(svA + dv);
    if (vA > m) { float r = __expf(m - vA); ax *= r; ay *= r; z *= r; m = vA; }
    float wA = __expf(vA - m);
    float2 fA = __half22float2(hA);
    z += wA; ax += wA * fA.x; ay += wA * fA.y;
    float vB = lrelu(svB + dv);
    if (vB > m) { float r = __expf(m - vB); ax *= r; ay *= r; z *= r; m = vB; }
    float wB = __expf(vB - m);
    float2 fB = __half22float2(hB);
    z += wB; ax += wB * fB.x; ay += wB * fB.y;
  }
  for (; i < hi; ++i) {
    const int s = src_sorted[i];
    const float sv = s1[s * HEADS1 + h];
    const __half2 hv = *(const __half2*)&h1[(size_t)s * C1 + c0];
    float v = lrelu(sv + dv);
    if (v > m) { float r = __expf(m - v); ax *= r; ay *= r; z *= r; m = v; }
    float w = __expf(v - m);
    float2 f = __half22float2(hv);
    z += w; ax += w * f.x; ay += w * f.y;
  }
  const float zinv = 1.f / (z + 1e-16f);
  float ox = ax * zinv + b1[c0];
  float oy = ay * zinv + b1[c0 + 1];
  ox = ox > 0.f ? ox : expm1f(ox);
  oy = oy > 0.f ? oy : expm1f(oy);
  *(__half2*)&x2h[(size_t)n * C1 + c0] = __floats2half2_rn(ox, oy);
}

__global__ __launch_bounds__(256) void agg2_fused(
    const int* __restrict__ row_start, const int* __restrict__ src_sorted,
    const float* __restrict__ s2, const float* __restrict__ d2,
    const __half* __restrict__ h2, const float* __restrict__ b2,
    float* __restrict__ out, int N) {
  const int n = blockIdx.x * 4 + (threadIdx.x >> 6);
  if (n >= N) return;
  const int lane = threadIdx.x & 63;
  const float dv = d2[n];
  const int lo = row_start[n], hi = row_start[n + 1];
  float m = -INFINITY, z = 0.f, acc = 0.f;
  int i = lo;
  for (; i + 2 <= hi; i += 2) {
    const int sA = src_sorted[i], sB = src_sorted[i + 1];
    const float svA = s2[sA];
    const float svB = s2[sB];
    const float hA = __half2float(h2[(size_t)sA * C2 + lane]);
    const float hB = __half2float(h2[(size_t)sB * C2 + lane]);
    float vA = lrelu(svA + dv);
    if (vA > m) { float r = __expf(m - vA); acc *= r; z *= r; m = vA; }
    float wA = __expf(vA - m);
    z += wA; acc += wA * hA;
    float vB = lrelu(svB + dv);
    if (vB > m) { float r = __expf(m - vB); acc *= r; z *= r; m = vB; }
    float wB = __expf(vB - m);
    z += wB; acc += wB * hB;
  }
  for (; i < hi; ++i) {
    const int s = src_sorted[i];
    const float sv = s2[s];
    const float hv = __half2float(h2[(size_t)s * C2 + lane]);
    float v = lrelu(sv + dv);
    if (v > m) { float r = __expf(m - v); acc *= r; z *= r; m = v; }
    float w = __expf(v - m);
    z += w; acc += w * hv;
  }
  out[(size_t)n * C2 + lane] = acc / (z + 1e-16f) + b2[lane];
}

extern "C" void kernel_launch(void* const* d_in, const int* in_sizes, int n_in,
                              void* d_out, int out_size, void* d_ws, size_t ws_size,
                              hipStream_t stream) {
  const float* x      = (const float*)d_in[0];
  const int*   ei     = (const int*)d_in[1];
  const float* W1     = (const float*)d_in[2];
  const float* a_src1 = (const float*)d_in[3];
  const float* a_dst1 = (const float*)d_in[4];
  const float* b1     = (const float*)d_in[5];
  const float* W2     = (const float*)d_in[6];
  const float* a_src2 = (const float*)d_in[7];
  const float* a_dst2 = (const float*)d_in[8];
  const float* b2     = (const float*)d_in[9];
  float* out = (float*)d_out;

  const int N = in_sizes[0] / INCH;
  const int E = in_sizes[1] / 2;
  const int* src = ei;
  const int* dst = ei + E;

  // Workspace layout (~45 MB)
  float* ws = (float*)d_ws;
  size_t o = 0;
  __half* xh  = (__half*)(ws + o); o += (size_t)N * C1 / 2;   // x in fp16
  __half* h1  = (__half*)(ws + o); o += (size_t)N * C1 / 2;   // layer-1 features fp16
  __half* x2h = (__half*)(ws + o); o += (size_t)N * C1 / 2;   // layer-2 input fp16
  float*  s1  = ws + o;            o += (size_t)N * HEADS1;
  float*  d1  = ws + o;            o += (size_t)N * HEADS1;
  __half* W1t = (__half*)(ws + o); o += 128 * 128 / 2;        // W1^T fp16 [128][128]
  __half* W2t = (__half*)(ws + o); o += 64 * 128 / 2;         // W2^T fp16 [64][128]
  int* deg        = (int*)(ws + o); o += N;                   // reused as cursor
  int* row_start  = (int*)(ws + o); o += N + 1;
  int* partial    = (int*)(ws + o); o += SB;
  int* src_sorted = (int*)(ws + o); o += E;
  // layer-2 aliases into h1's region (h1 dead after agg1_fused)
  __half* h2 = h1;                                   // N*64 halves
  float*  s2 = (float*)h1 + (size_t)N * 32;          // N floats (after h2)
  float*  d2 = s2 + N;                               // N floats

  const int EB = (E + 255) / 256;
  const int NB64 = (N + 63) / 64;

  // prep: fp16 conversions
  cvt_fp16<<<(N * C1 / 8 + 255) / 256, 256, 0, stream>>>(x, xh, N * C1 / 8);
  transpose_fp16<<<(128 * 128 + 255) / 256, 256, 0, stream>>>(W1, W1t, 128, 128);
  transpose_fp16<<<(64 * 128 + 255) / 256, 256, 0, stream>>>(W2, W2t, 128, 64);

  // CSR build
  hipMemsetAsync(deg, 0, (size_t)N * 4, stream);
  hist_kernel<<<EB, 256, 0, stream>>>(dst, deg, E);
  scan1_kernel<<<SB, SB, 0, stream>>>(deg, partial, N);
  scan2_kernel<<<1, SB, 0, stream>>>(partial);
  scan3_kernel<<<SB, SB, 0, stream>>>(deg, partial, row_start, N);
  hipMemsetAsync(deg, 0, (size_t)N * 4, stream);
  fill_kernel<<<EB, 256, 0, stream>>>(src, dst, row_start, deg, src_sorted, E);

  // Layer 1
  gemm1_mfma<<<NB64, 256, 0, stream>>>(xh, W1t, a_src1, a_dst1, h1, s1, d1, N);
  agg1_fused<<<(N + 3) / 4, 256, 0, stream>>>(row_start, src_sorted, s1, d1, h1, b1, x2h, N);

  // Layer 2
  gemm2_mfma<<<NB64, 256, 0, stream>>>(x2h, W2t, a_src2, a_dst2, h2, s2, d2, N);
  agg2_fused<<<(N + 3) / 4, 256, 0, stream>>>(row_start, src_sorted, s2, d2, h2, b2, out, N);
}

// Round 7
// 241.544 us; speedup vs baseline: 1.0487x; 1.0487x over previous
//
#include <hip/hip_runtime.h>
#include <hip/hip_fp16.h>

#define INCH   128
#define HEADS1 8
#define HID1   16
#define C1     128   // HEADS1*HID1
#define C2     64
#define NEG_SLOPE 0.2f
#define SB     256   // scan blocks / threads

using f16x8 = __attribute__((ext_vector_type(8))) _Float16;
using f32x4 = __attribute__((ext_vector_type(4))) float;

__device__ __forceinline__ float lrelu(float v) { return v >= 0.f ? v : NEG_SLOPE * v; }
// byte-offset swizzle within a 256B LDS row (rows are 128 fp16)
__device__ __forceinline__ int swzA(int row, int byteInRow) {
  return (row << 8) | (byteInRow ^ ((row & 15) << 4));
}

// ---------------- prep: fp32 -> fp16 conversions ----------------

__global__ void cvt_fp16(const float* __restrict__ in, __half* __restrict__ o, int total8) {
  int i = blockIdx.x * blockDim.x + threadIdx.x;
  if (i >= total8) return;
  const float4* p = (const float4*)in + (size_t)i * 2;
  float4 v0 = p[0], v1 = p[1];
  __half2 ha = __floats2half2_rn(v0.x, v0.y);
  __half2 hb = __floats2half2_rn(v0.z, v0.w);
  __half2 hc = __floats2half2_rn(v1.x, v1.y);
  __half2 hd = __floats2half2_rn(v1.z, v1.w);
  uint4 w = { *(unsigned*)&ha, *(unsigned*)&hb, *(unsigned*)&hc, *(unsigned*)&hd };
  ((uint4*)o)[i] = w;
}

// W[K][Ncol] (row-major fp32) -> Wt[Ncol][K] (fp16)
__global__ void transpose_fp16(const float* __restrict__ W, __half* __restrict__ Wt,
                               int K, int Ncol) {
  int id = blockIdx.x * blockDim.x + threadIdx.x;
  if (id >= K * Ncol) return;
  int col = id / K, k = id % K;
  Wt[id] = __float2half(W[k * Ncol + col]);
}

// ---------------- CSR build (by destination) ----------------

__global__ void hist_kernel(const int* __restrict__ dst, int* __restrict__ deg, int E) {
  int e = blockIdx.x * blockDim.x + threadIdx.x;
  if (e < E) atomicAdd(&deg[dst[e]], 1);
}

__global__ void scan1_kernel(const int* __restrict__ deg, int* __restrict__ partial, int N) {
  __shared__ int sh[SB];
  const int b = blockIdx.x, t = threadIdx.x;
  const int chunk = (N + SB - 1) / SB;
  const int lo = b * chunk, hi = min(lo + chunk, N);
  int s = 0;
  for (int i = lo + t; i < hi; i += SB) s += deg[i];
  sh[t] = s;
  __syncthreads();
  for (int off = SB / 2; off; off >>= 1) {
    if (t < off) sh[t] += sh[t + off];
    __syncthreads();
  }
  if (t == 0) partial[b] = sh[0];
}

__global__ void scan2_kernel(int* __restrict__ partial) {
  __shared__ int sh[SB];
  const int t = threadIdx.x;
  int v = partial[t];
  sh[t] = v;
  __syncthreads();
  for (int off = 1; off < SB; off <<= 1) {
    int u = (t >= off) ? sh[t - off] : 0;
    __syncthreads();
    sh[t] += u;
    __syncthreads();
  }
  partial[t] = sh[t] - v;
}

__global__ void scan3_kernel(const int* __restrict__ deg, const int* __restrict__ partial,
                             int* __restrict__ row_start, int N) {
  __shared__ int sh[SB];
  const int b = blockIdx.x, t = threadIdx.x;
  const int chunk = (N + SB - 1) / SB;
  const int lo = b * chunk, hi = min(lo + chunk, N);
  int run = partial[b];
  for (int base = lo; base < hi; base += SB) {
    int i = base + t;
    int v = (i < hi) ? deg[i] : 0;
    sh[t] = v;
    __syncthreads();
    for (int off = 1; off < SB; off <<= 1) {
      int u = (t >= off) ? sh[t - off] : 0;
      __syncthreads();
      sh[t] += u;
      __syncthreads();
    }
    if (i < hi) row_start[i] = run + sh[t] - v;
    run += sh[SB - 1];
    __syncthreads();
  }
  if (b == SB - 1 && t == 0) row_start[N] = run;
}

__global__ void fill_kernel(const int* __restrict__ src, const int* __restrict__ dst,
                            const int* __restrict__ row_start, int* __restrict__ cursor,
                            int* __restrict__ src_sorted, int E) {
  int e = blockIdx.x * blockDim.x + threadIdx.x;
  if (e >= E) return;
  int d = dst[e];
  int slot = row_start[d] + atomicAdd(&cursor[d], 1);
  src_sorted[slot] = src[e];
}

// ---------------- MFMA GEMMs ----------------
// gemm1: [M x 128] x [128 x 128]; 256 thr = 4 waves; block does 64 rows x 128 cols.
__global__ __launch_bounds__(256) void gemm1_mfma(
    const __half* __restrict__ xh, const __half* __restrict__ W1t,
    const float* __restrict__ a_src, const float* __restrict__ a_dst,
    __half* __restrict__ h1, float* __restrict__ s1, float* __restrict__ d1, int M) {
  __shared__ unsigned char As[16384];   // 64 x 128 fp16, swizzled
  __shared__ unsigned char Bs[32768];   // 128 x 128 fp16 (col-major W1), swizzled
  const int t = threadIdx.x;
  const int m0 = blockIdx.x * 64;
  for (int c = t; c < 1024; c += 256) {
    int row = c >> 4, seg = c & 15;
    int gr = m0 + row;
    uint4 v = make_uint4(0, 0, 0, 0);
    if (gr < M) v = ((const uint4*)xh)[(size_t)gr * 16 + seg];
    *(uint4*)(As + swzA(row, seg << 4)) = v;
  }
  for (int c = t; c < 2048; c += 256) {
    int row = c >> 4, seg = c & 15;
    uint4 v = ((const uint4*)W1t)[(row << 4) + seg];
    *(uint4*)(Bs + swzA(row, seg << 4)) = v;
  }
  __syncthreads();
  const int l = t & 63, wid = t >> 6;
  const int c16 = l & 15;                 // col / row-low nibble
  const int kOff = (l >> 4) << 4;         // byte offset of this lane's 8 k-elems
  const int rA = (wid << 4) | c16;
  f16x8 a[4];
#pragma unroll
  for (int kb = 0; kb < 4; ++kb)
    a[kb] = *(const f16x8*)(As + swzA(rA, (kb << 6) + kOff));
#pragma unroll
  for (int ct = 0; ct < 8; ++ct) {        // ct == head (HID1 == 16)
    const int rB = (ct << 4) | c16;
    f32x4 acc = {0.f, 0.f, 0.f, 0.f};
#pragma unroll
    for (int kb = 0; kb < 4; ++kb) {
      f16x8 b = *(const f16x8*)(Bs + swzA(rB, (kb << 6) + kOff));
      acc = __builtin_amdgcn_mfma_f32_16x16x32_f16(a[kb], b, acc, 0, 0, 0);
    }
    const int colg = (ct << 4) + c16;
    const float asv = a_src[colg], adv = a_dst[colg];
#pragma unroll
    for (int i = 0; i < 4; ++i) {
      const int n = m0 + (wid << 4) + ((l >> 4) << 2) + i;
      float v = acc[i];
      float sv = v * asv, dv = v * adv;
      sv += __shfl_xor(sv, 1); sv += __shfl_xor(sv, 2);
      sv += __shfl_xor(sv, 4); sv += __shfl_xor(sv, 8);
      dv += __shfl_xor(dv, 1); dv += __shfl_xor(dv, 2);
      dv += __shfl_xor(dv, 4); dv += __shfl_xor(dv, 8);
      if (n < M) {
        h1[(size_t)n * C1 + colg] = __float2half(v);
        if (c16 == 0) { s1[n * HEADS1 + ct] = sv; d1[n * HEADS1 + ct] = dv; }
      }
    }
  }
}

// gemm2: [M x 128] x [128 x 64]
__global__ __launch_bounds__(256) void gemm2_mfma(
    const __half* __restrict__ x2h, const __half* __restrict__ W2t,
    const float* __restrict__ a_src, const float* __restrict__ a_dst,
    __half* __restrict__ h2, float* __restrict__ s2, float* __restrict__ d2, int M) {
  __shared__ unsigned char As[16384];   // 64 x 128 fp16
  __shared__ unsigned char Bs[16384];   // 64 x 128 fp16 (col-major W2)
  const int t = threadIdx.x;
  const int m0 = blockIdx.x * 64;
  for (int c = t; c < 1024; c += 256) {
    int row = c >> 4, seg = c & 15;
    int gr = m0 + row;
    uint4 v = make_uint4(0, 0, 0, 0);
    if (gr < M) v = ((const uint4*)x2h)[(size_t)gr * 16 + seg];
    *(uint4*)(As + swzA(row, seg << 4)) = v;
  }
  for (int c = t; c < 1024; c += 256) {
    int row = c >> 4, seg = c & 15;
    uint4 v = ((const uint4*)W2t)[(row << 4) + seg];
    *(uint4*)(Bs + swzA(row, seg << 4)) = v;
  }
  __syncthreads();
  const int l = t & 63, wid = t >> 6;
  const int c16 = l & 15;
  const int kOff = (l >> 4) << 4;
  const int rA = (wid << 4) | c16;
  f16x8 a[4];
#pragma unroll
  for (int kb = 0; kb < 4; ++kb)
    a[kb] = *(const f16x8*)(As + swzA(rA, (kb << 6) + kOff));
  float svp[4] = {0.f, 0.f, 0.f, 0.f};
  float dvp[4] = {0.f, 0.f, 0.f, 0.f};
#pragma unroll
  for (int ct = 0; ct < 4; ++ct) {
    const int rB = (ct << 4) | c16;
    f32x4 acc = {0.f, 0.f, 0.f, 0.f};
#pragma unroll
    for (int kb = 0; kb < 4; ++kb) {
      f16x8 b = *(const f16x8*)(Bs + swzA(rB, (kb << 6) + kOff));
      acc = __builtin_amdgcn_mfma_f32_16x16x32_f16(a[kb], b, acc, 0, 0, 0);
    }
    const int colg = (ct << 4) + c16;
    const float asv = a_src[colg], adv = a_dst[colg];
#pragma unroll
    for (int i = 0; i < 4; ++i) {
      const int n = m0 + (wid << 4) + ((l >> 4) << 2) + i;
      float v = acc[i];
      svp[i] += v * asv;
      dvp[i] += v * adv;
      if (n < M) h2[(size_t)n * C2 + colg] = __float2half(v);
    }
  }
#pragma unroll
  for (int i = 0; i < 4; ++i) {
    float sv = svp[i], dv = dvp[i];
    sv += __shfl_xor(sv, 1); sv += __shfl_xor(sv, 2);
    sv += __shfl_xor(sv, 4); sv += __shfl_xor(sv, 8);
    dv += __shfl_xor(dv, 1); dv += __shfl_xor(dv, 2);
    dv += __shfl_xor(dv, 4); dv += __shfl_xor(dv, 8);
    const int n = m0 + (wid << 4) + ((l >> 4) << 2) + i;
    if (c16 == 0 && n < M) { s2[n] = sv; d2[n] = dv; }
  }
}

// ---------------- Attention weights (wave per node) ----------------

__global__ void attn1_kernel(const int* __restrict__ row_start, const int* __restrict__ src_sorted,
                             const float* __restrict__ s1, float* d1z,
                             __half* __restrict__ wbuf, int N) {
  const int wave = threadIdx.x >> 6;
  const int n = blockIdx.x * 4 + wave;
  if (n >= N) return;
  const int lane = threadIdx.x & 63;
  const int le = lane >> 3, h = lane & 7;
  const int lo = row_start[n], hi = row_start[n + 1];
  const float dv = d1z[n * HEADS1 + h];
  float m = -INFINITY;
  for (int i = lo + le; i < hi; i += 8)
    m = fmaxf(m, lrelu(s1[src_sorted[i] * HEADS1 + h] + dv));
#pragma unroll
  for (int off = 8; off < 64; off <<= 1) m = fmaxf(m, __shfl_xor(m, off));
  if (!isfinite(m)) m = 0.f;
  float z = 0.f;
  for (int i = lo + le; i < hi; i += 8) {
    float w = __expf(lrelu(s1[src_sorted[i] * HEADS1 + h] + dv) - m);
    wbuf[(size_t)i * HEADS1 + h] = __float2half(w);
    z += w;
  }
#pragma unroll
  for (int off = 8; off < 64; off <<= 1) z += __shfl_xor(z, off);
  if (le == 0) d1z[n * HEADS1 + h] = z;
}

__global__ void attn2_kernel(const int* __restrict__ row_start, const int* __restrict__ src_sorted,
                             const float* __restrict__ s2, float* d2z,
                             __half* __restrict__ wbuf2, int N) {
  const int wave = threadIdx.x >> 6;
  const int n = blockIdx.x * 4 + wave;
  if (n >= N) return;
  const int lane = threadIdx.x & 63;
  const int lo = row_start[n], hi = row_start[n + 1];
  const float dv = d2z[n];
  float m = -INFINITY;
  for (int i = lo + lane; i < hi; i += 64)
    m = fmaxf(m, lrelu(s2[src_sorted[i]] + dv));
#pragma unroll
  for (int off = 1; off < 64; off <<= 1) m = fmaxf(m, __shfl_xor(m, off));
  if (!isfinite(m)) m = 0.f;
  float z = 0.f;
  for (int i = lo + lane; i < hi; i += 64) {
    float w = __expf(lrelu(s2[src_sorted[i]] + dv) - m);
    wbuf2[i] = __float2half(w);
    z += w;
  }
#pragma unroll
  for (int off = 1; off < 64; off <<= 1) z += __shfl_xor(z, off);
  if (lane == 0) d2z[n] = z;
}

// ---------------- Wide weighted aggregation ----------------
// agg1: one wave per node. Lane l: edge-slot es=l>>4 (4 edges in parallel),
// channel block cl=l&15 (8 fp16 = 16B per lane -> 16 lanes cover the 256B row).
__global__ __launch_bounds__(256) void agg1_wide(
    const int* __restrict__ row_start, const int* __restrict__ src_sorted,
    const __half* __restrict__ wbuf, const float* __restrict__ z1n,
    const __half* __restrict__ h1, const float* __restrict__ b1,
    __half* __restrict__ x2h, int N) {
  const int n = blockIdx.x * 4 + (threadIdx.x >> 6);
  if (n >= N) return;
  const int l = threadIdx.x & 63;
  const int es = l >> 4, cl = l & 15;
  const int h = cl >> 1;
  const int lo = row_start[n], hi = row_start[n + 1];
  float acc[8] = {0.f, 0.f, 0.f, 0.f, 0.f, 0.f, 0.f, 0.f};
  for (int i = lo; i < hi; i += 8) {
    const int eA = i + es, eB = i + 4 + es;
    const int ca = min(eA, hi - 1), cb = min(eB, hi - 1);
    const int sA = src_sorted[ca], sB = src_sorted[cb];
    const float wA = (eA < hi) ? __half2float(wbuf[(size_t)eA * HEADS1 + h]) : 0.f;
    const float wB = (eB < hi) ? __half2float(wbuf[(size_t)eB * HEADS1 + h]) : 0.f;
    const uint4 fA = ((const uint4*)h1)[(size_t)sA * 16 + cl];
    const uint4 fB = ((const uint4*)h1)[(size_t)sB * 16 + cl];
    const __half2* pA = (const __half2*)&fA;
    const __half2* pB = (const __half2*)&fB;
#pragma unroll
    for (int k = 0; k < 4; ++k) {
      float2 a2 = __half22float2(pA[k]);
      float2 b2v = __half22float2(pB[k]);
      acc[2 * k]     += wA * a2.x + wB * b2v.x;
      acc[2 * k + 1] += wA * a2.y + wB * b2v.y;
    }
  }
#pragma unroll
  for (int k = 0; k < 8; ++k) {
    acc[k] += __shfl_xor(acc[k], 16);
    acc[k] += __shfl_xor(acc[k], 32);
  }
  if (es == 0) {
    const float zinv = 1.f / (z1n[n * HEADS1 + h] + 1e-16f);
    __half2 o[4];
#pragma unroll
    for (int k = 0; k < 4; ++k) {
      float ox = acc[2 * k] * zinv + b1[(cl << 3) + 2 * k];
      float oy = acc[2 * k + 1] * zinv + b1[(cl << 3) + 2 * k + 1];
      ox = ox > 0.f ? ox : expm1f(ox);
      oy = oy > 0.f ? oy : expm1f(oy);
      o[k] = __floats2half2_rn(ox, oy);
    }
    ((uint4*)x2h)[(size_t)n * 16 + cl] = *(const uint4*)o;
  }
}

// agg2: one wave per node. es=l>>3 (8 edges), cl=l&7 (8 fp16 = 16B; 8 lanes cover 128B row).
__global__ __launch_bounds__(256) void agg2_wide(
    const int* __restrict__ row_start, const int* __restrict__ src_sorted,
    const __half* __restrict__ wbuf2, const float* __restrict__ z2n,
    const __half* __restrict__ h2, const float* __restrict__ b2,
    float* __restrict__ out, int N) {
  const int n = blockIdx.x * 4 + (threadIdx.x >> 6);
  if (n >= N) return;
  const int l = threadIdx.x & 63;
  const int es = l >> 3, cl = l & 7;
  const int lo = row_start[n], hi = row_start[n + 1];
  float acc[8] = {0.f, 0.f, 0.f, 0.f, 0.f, 0.f, 0.f, 0.f};
  for (int i = lo; i < hi; i += 16) {
    const int eA = i + es, eB = i + 8 + es;
    const int ca = min(eA, hi - 1), cb = min(eB, hi - 1);
    const int sA = src_sorted[ca], sB = src_sorted[cb];
    const float wA = (eA < hi) ? __half2float(wbuf2[eA]) : 0.f;
    const float wB = (eB < hi) ? __half2float(wbuf2[eB]) : 0.f;
    const uint4 fA = ((const uint4*)h2)[(size_t)sA * 8 + cl];
    const uint4 fB = ((const uint4*)h2)[(size_t)sB * 8 + cl];
    const __half2* pA = (const __half2*)&fA;
    const __half2* pB = (const __half2*)&fB;
#pragma unroll
    for (int k = 0; k < 4; ++k) {
      float2 a2 = __half22float2(pA[k]);
      float2 b2v = __half22float2(pB[k]);
      acc[2 * k]     += wA * a2.x + wB * b2v.x;
      acc[2 * k + 1] += wA * a2.y + wB * b2v.y;
    }
  }
#pragma unroll
  for (int k = 0; k < 8; ++k) {
    acc[k] += __shfl_xor(acc[k], 8);
    acc[k] += __shfl_xor(acc[k], 16);
    acc[k] += __shfl_xor(acc[k], 32);
  }
  if (es == 0) {
    const float zinv = 1.f / (z2n[n] + 1e-16f);
    float4 o0, o1;
    o0.x = acc[0] * zinv + b2[(cl << 3) + 0];
    o0.y = acc[1] * zinv + b2[(cl << 3) + 1];
    o0.z = acc[2] * zinv + b2[(cl << 3) + 2];
    o0.w = acc[3] * zinv + b2[(cl << 3) + 3];
    o1.x = acc[4] * zinv + b2[(cl << 3) + 4];
    o1.y = acc[5] * zinv + b2[(cl << 3) + 5];
    o1.z = acc[6] * zinv + b2[(cl << 3) + 6];
    o1.w = acc[7] * zinv + b2[(cl << 3) + 7];
    float4* po = (float4*)&out[(size_t)n * C2 + (cl << 3)];
    po[0] = o0;
    po[1] = o1;
  }
}

extern "C" void kernel_launch(void* const* d_in, const int* in_sizes, int n_in,
                              void* d_out, int out_size, void* d_ws, size_t ws_size,
                              hipStream_t stream) {
  const float* x      = (const float*)d_in[0];
  const int*   ei     = (const int*)d_in[1];
  const float* W1     = (const float*)d_in[2];
  const float* a_src1 = (const float*)d_in[3];
  const float* a_dst1 = (const float*)d_in[4];
  const float* b1     = (const float*)d_in[5];
  const float* W2     = (const float*)d_in[6];
  const float* a_src2 = (const float*)d_in[7];
  const float* a_dst2 = (const float*)d_in[8];
  const float* b2     = (const float*)d_in[9];
  float* out = (float*)d_out;

  const int N = in_sizes[0] / INCH;
  const int E = in_sizes[1] / 2;
  const int* src = ei;
  const int* dst = ei + E;

  // Workspace layout (~58 MB; >=71 MB proven available in round 1)
  float* ws = (float*)d_ws;
  size_t o = 0;
  __half* xh  = (__half*)(ws + o); o += (size_t)N * C1 / 2;   // x in fp16
  __half* h1  = (__half*)(ws + o); o += (size_t)N * C1 / 2;   // layer-1 features fp16
  __half* x2h = (__half*)(ws + o); o += (size_t)N * C1 / 2;   // layer-2 input fp16
  float*  s1  = ws + o;            o += (size_t)N * HEADS1;
  float*  d1  = ws + o;            o += (size_t)N * HEADS1;   // becomes z1 after attn1
  __half* wbuf = (__half*)(ws + o); o += (size_t)E * HEADS1 / 2;
  __half* W1t = (__half*)(ws + o); o += 128 * 128 / 2;        // W1^T fp16 [128][128]
  __half* W2t = (__half*)(ws + o); o += 64 * 128 / 2;         // W2^T fp16 [64][128]
  int* deg        = (int*)(ws + o); o += N;                   // reused as cursor
  int* row_start  = (int*)(ws + o); o += N + 1;
  int* partial    = (int*)(ws + o); o += SB;
  int* src_sorted = (int*)(ws + o); o += E;
  // layer-2 aliases into h1's region (h1 dead after agg1_wide)
  __half* h2 = h1;                                   // N*64 halves
  float*  s2 = (float*)h1 + (size_t)N * 32;          // N floats (after h2)
  float*  d2 = s2 + N;                               // N floats, becomes z2
  __half* wbuf2 = wbuf;

  const int EB = (E + 255) / 256;
  const int NB64 = (N + 63) / 64;

  // prep: fp16 conversions
  cvt_fp16<<<(N * C1 / 8 + 255) / 256, 256, 0, stream>>>(x, xh, N * C1 / 8);
  transpose_fp16<<<(128 * 128 + 255) / 256, 256, 0, stream>>>(W1, W1t, 128, 128);
  transpose_fp16<<<(64 * 128 + 255) / 256, 256, 0, stream>>>(W2, W2t, 128, 64);

  // CSR build
  hipMemsetAsync(deg, 0, (size_t)N * 4, stream);
  hist_kernel<<<EB, 256, 0, stream>>>(dst, deg, E);
  scan1_kernel<<<SB, SB, 0, stream>>>(deg, partial, N);
  scan2_kernel<<<1, SB, 0, stream>>>(partial);
  scan3_kernel<<<SB, SB, 0, stream>>>(deg, partial, row_start, N);
  hipMemsetAsync(deg, 0, (size_t)N * 4, stream);
  fill_kernel<<<EB, 256, 0, stream>>>(src, dst, row_start, deg, src_sorted, E);

  // Layer 1
  gemm1_mfma<<<NB64, 256, 0, stream>>>(xh, W1t, a_src1, a_dst1, h1, s1, d1, N);
  attn1_kernel<<<(N + 3) / 4, 256, 0, stream>>>(row_start, src_sorted, s1, d1, wbuf, N);
  agg1_wide<<<(N + 3) / 4, 256, 0, stream>>>(row_start, src_sorted, wbuf, d1, h1, b1, x2h, N);

  // Layer 2
  gemm2_mfma<<<NB64, 256, 0, stream>>>(x2h, W2t, a_src2, a_dst2, h2, s2, d2, N);
  attn2_kernel<<<(N + 3) / 4, 256, 0, stream>>>(row_start, src_sorted, s2, d2, wbuf2, N);
  agg2_wide<<<(N + 3) / 4, 256, 0, stream>>>(row_start, src_sorted, wbuf2, d2, h2, b2, out, N);
}

// Round 8
// 223.528 us; speedup vs baseline: 1.1333x; 1.0806x over previous
//
#include <hip/hip_runtime.h>
#include <hip/hip_fp16.h>

#define INCH   128
#define HEADS1 8
#define HID1   16
#define C1     128   // HEADS1*HID1
#define C2     64
#define NEG_SLOPE 0.2f
#define SB     256   // scan blocks / threads

using f16x8 = __attribute__((ext_vector_type(8))) _Float16;
using f32x4 = __attribute__((ext_vector_type(4))) float;

__device__ __forceinline__ float lrelu(float v) { return v >= 0.f ? v : NEG_SLOPE * v; }
// byte-offset swizzle within a 256B LDS row (rows are 128 fp16)
__device__ __forceinline__ int swzA(int row, int byteInRow) {
  return (row << 8) | (byteInRow ^ ((row & 15) << 4));
}

// ---------------- fused prep: x->fp16, W1/W2 transpose->fp16, dst histogram ----------------

__global__ void prep_kernel(const float* __restrict__ x, __half* __restrict__ xh,
                            const float* __restrict__ W1, __half* __restrict__ W1t,
                            const float* __restrict__ W2, __half* __restrict__ W2t,
                            const int* __restrict__ dst, int* __restrict__ deg,
                            int cvtB, int tB, int total8, int E) {
  const int b = blockIdx.x, t = threadIdx.x;
  if (b < cvtB) {
    int i = b * 256 + t;
    if (i >= total8) return;
    const float4* p = (const float4*)x + (size_t)i * 2;
    float4 v0 = p[0], v1 = p[1];
    __half2 ha = __floats2half2_rn(v0.x, v0.y);
    __half2 hb = __floats2half2_rn(v0.z, v0.w);
    __half2 hc = __floats2half2_rn(v1.x, v1.y);
    __half2 hd = __floats2half2_rn(v1.z, v1.w);
    uint4 w = { *(unsigned*)&ha, *(unsigned*)&hb, *(unsigned*)&hc, *(unsigned*)&hd };
    ((uint4*)xh)[i] = w;
  } else if (b < cvtB + tB) {
    int id = (b - cvtB) * 256 + t;
    if (id < 128 * 128) {
      int col = id >> 7, k = id & 127;
      W1t[id] = __float2half(W1[k * 128 + col]);
    } else if (id < 128 * 128 + 64 * 128) {
      int idx = id - 128 * 128;
      int col = idx >> 7, k = idx & 127;
      W2t[idx] = __float2half(W2[k * 64 + col]);
    }
  } else {
    int e = (b - cvtB - tB) * 256 + t;
    if (e < E) atomicAdd(&deg[dst[e]], 1);
  }
}

// ---------------- CSR build (by destination) ----------------

__global__ void scan1_kernel(const int* __restrict__ deg, int* __restrict__ partial, int N) {
  __shared__ int sh[SB];
  const int b = blockIdx.x, t = threadIdx.x;
  const int chunk = (N + SB - 1) / SB;
  const int lo = b * chunk, hi = min(lo + chunk, N);
  int s = 0;
  for (int i = lo + t; i < hi; i += SB) s += deg[i];
  sh[t] = s;
  __syncthreads();
  for (int off = SB / 2; off; off >>= 1) {
    if (t < off) sh[t] += sh[t + off];
    __syncthreads();
  }
  if (t == 0) partial[b] = sh[0];
}

// stage 2+3 fused: each block locally scans the 256 partials, then scans its chunk.
__global__ void scan3_kernel(const int* __restrict__ deg, const int* __restrict__ partial,
                             int* __restrict__ row_start, int N) {
  __shared__ int pref[SB];
  __shared__ int sh[SB];
  const int b = blockIdx.x, t = threadIdx.x;
  int pv = partial[t];
  pref[t] = pv;
  __syncthreads();
  for (int off = 1; off < SB; off <<= 1) {
    int u = (t >= off) ? pref[t - off] : 0;
    __syncthreads();
    pref[t] += u;
    __syncthreads();
  }
  const int chunk = (N + SB - 1) / SB;
  const int lo = b * chunk, hi = min(lo + chunk, N);
  int run = (b == 0) ? 0 : pref[b - 1];
  for (int base = lo; base < hi; base += SB) {
    int i = base + t;
    int v = (i < hi) ? deg[i] : 0;
    sh[t] = v;
    __syncthreads();
    for (int off = 1; off < SB; off <<= 1) {
      int u = (t >= off) ? sh[t - off] : 0;
      __syncthreads();
      sh[t] += u;
      __syncthreads();
    }
    if (i < hi) row_start[i] = run + sh[t] - v;
    run += sh[SB - 1];
    __syncthreads();
  }
  if (b == SB - 1 && t == 0) row_start[N] = run;
}

__global__ void fill_kernel(const int* __restrict__ src, const int* __restrict__ dst,
                            const int* __restrict__ row_start, int* __restrict__ cursor,
                            int* __restrict__ src_sorted, int E) {
  int e = blockIdx.x * blockDim.x + threadIdx.x;
  if (e >= E) return;
  int d = dst[e];
  int slot = row_start[d] + atomicAdd(&cursor[d], 1);
  src_sorted[slot] = src[e];
}

// ---------------- MFMA GEMMs ----------------
// gemm1: [M x 128] x [128 x 128]; 256 thr = 4 waves; block does 64 rows x 128 cols.
__global__ __launch_bounds__(256) void gemm1_mfma(
    const __half* __restrict__ xh, const __half* __restrict__ W1t,
    const float* __restrict__ a_src, const float* __restrict__ a_dst,
    __half* __restrict__ h1, float* __restrict__ s1, float* __restrict__ d1, int M) {
  __shared__ unsigned char As[16384];   // 64 x 128 fp16, swizzled
  __shared__ unsigned char Bs[32768];   // 128 x 128 fp16 (col-major W1), swizzled
  const int t = threadIdx.x;
  const int m0 = blockIdx.x * 64;
  for (int c = t; c < 1024; c += 256) {
    int row = c >> 4, seg = c & 15;
    int gr = m0 + row;
    uint4 v = make_uint4(0, 0, 0, 0);
    if (gr < M) v = ((const uint4*)xh)[(size_t)gr * 16 + seg];
    *(uint4*)(As + swzA(row, seg << 4)) = v;
  }
  for (int c = t; c < 2048; c += 256) {
    int row = c >> 4, seg = c & 15;
    uint4 v = ((const uint4*)W1t)[(row << 4) + seg];
    *(uint4*)(Bs + swzA(row, seg << 4)) = v;
  }
  __syncthreads();
  const int l = t & 63, wid = t >> 6;
  const int c16 = l & 15;
  const int kOff = (l >> 4) << 4;
  const int rA = (wid << 4) | c16;
  f16x8 a[4];
#pragma unroll
  for (int kb = 0; kb < 4; ++kb)
    a[kb] = *(const f16x8*)(As + swzA(rA, (kb << 6) + kOff));
#pragma unroll
  for (int ct = 0; ct < 8; ++ct) {        // ct == head (HID1 == 16)
    const int rB = (ct << 4) | c16;
    f32x4 acc = {0.f, 0.f, 0.f, 0.f};
#pragma unroll
    for (int kb = 0; kb < 4; ++kb) {
      f16x8 b = *(const f16x8*)(Bs + swzA(rB, (kb << 6) + kOff));
      acc = __builtin_amdgcn_mfma_f32_16x16x32_f16(a[kb], b, acc, 0, 0, 0);
    }
    const int colg = (ct << 4) + c16;
    const float asv = a_src[colg], adv = a_dst[colg];
#pragma unroll
    for (int i = 0; i < 4; ++i) {
      const int n = m0 + (wid << 4) + ((l >> 4) << 2) + i;
      float v = acc[i];
      float sv = v * asv, dv = v * adv;
      sv += __shfl_xor(sv, 1); sv += __shfl_xor(sv, 2);
      sv += __shfl_xor(sv, 4); sv += __shfl_xor(sv, 8);
      dv += __shfl_xor(dv, 1); dv += __shfl_xor(dv, 2);
      dv += __shfl_xor(dv, 4); dv += __shfl_xor(dv, 8);
      if (n < M) {
        h1[(size_t)n * C1 + colg] = __float2half(v);
        if (c16 == 0) { s1[n * HEADS1 + ct] = sv; d1[n * HEADS1 + ct] = dv; }
      }
    }
  }
}

// gemm2: [M x 128] x [128 x 64]
__global__ __launch_bounds__(256) void gemm2_mfma(
    const __half* __restrict__ x2h, const __half* __restrict__ W2t,
    const float* __restrict__ a_src, const float* __restrict__ a_dst,
    __half* __restrict__ h2, float* __restrict__ s2, float* __restrict__ d2, int M) {
  __shared__ unsigned char As[16384];   // 64 x 128 fp16
  __shared__ unsigned char Bs[16384];   // 64 x 128 fp16 (col-major W2)
  const int t = threadIdx.x;
  const int m0 = blockIdx.x * 64;
  for (int c = t; c < 1024; c += 256) {
    int row = c >> 4, seg = c & 15;
    int gr = m0 + row;
    uint4 v = make_uint4(0, 0, 0, 0);
    if (gr < M) v = ((const uint4*)x2h)[(size_t)gr * 16 + seg];
    *(uint4*)(As + swzA(row, seg << 4)) = v;
  }
  for (int c = t; c < 1024; c += 256) {
    int row = c >> 4, seg = c & 15;
    uint4 v = ((const uint4*)W2t)[(row << 4) + seg];
    *(uint4*)(Bs + swzA(row, seg << 4)) = v;
  }
  __syncthreads();
  const int l = t & 63, wid = t >> 6;
  const int c16 = l & 15;
  const int kOff = (l >> 4) << 4;
  const int rA = (wid << 4) | c16;
  f16x8 a[4];
#pragma unroll
  for (int kb = 0; kb < 4; ++kb)
    a[kb] = *(const f16x8*)(As + swzA(rA, (kb << 6) + kOff));
  float svp[4] = {0.f, 0.f, 0.f, 0.f};
  float dvp[4] = {0.f, 0.f, 0.f, 0.f};
#pragma unroll
  for (int ct = 0; ct < 4; ++ct) {
    const int rB = (ct << 4) | c16;
    f32x4 acc = {0.f, 0.f, 0.f, 0.f};
#pragma unroll
    for (int kb = 0; kb < 4; ++kb) {
      f16x8 b = *(const f16x8*)(Bs + swzA(rB, (kb << 6) + kOff));
      acc = __builtin_amdgcn_mfma_f32_16x16x32_f16(a[kb], b, acc, 0, 0, 0);
    }
    const int colg = (ct << 4) + c16;
    const float asv = a_src[colg], adv = a_dst[colg];
#pragma unroll
    for (int i = 0; i < 4; ++i) {
      const int n = m0 + (wid << 4) + ((l >> 4) << 2) + i;
      float v = acc[i];
      svp[i] += v * asv;
      dvp[i] += v * adv;
      if (n < M) h2[(size_t)n * C2 + colg] = __float2half(v);
    }
  }
#pragma unroll
  for (int i = 0; i < 4; ++i) {
    float sv = svp[i], dv = dvp[i];
    sv += __shfl_xor(sv, 1); sv += __shfl_xor(sv, 2);
    sv += __shfl_xor(sv, 4); sv += __shfl_xor(sv, 8);
    dv += __shfl_xor(dv, 1); dv += __shfl_xor(dv, 2);
    dv += __shfl_xor(dv, 4); dv += __shfl_xor(dv, 8);
    const int n = m0 + (wid << 4) + ((l >> 4) << 2) + i;
    if (c16 == 0 && n < M) { s2[n] = sv; d2[n] = dv; }
  }
}

// ---------------- Fused chunked softmax + wide aggregation ----------------
// layer1: one wave per node; chunks of 64 edges.
// Phase 1 layout: le=lane>>3 (edge slot j = r*8+le), h=lane&7 (head). One s1 gather,
//   chunk-max via shuffle, per-head rescale of running {z, acc} once per chunk.
// Phase 2 layout: es=lane>>4 (4 edge slots), cl=lane&15 (16B of the 256B h1 row).
__global__ __launch_bounds__(256) void layer1_agg(
    const int* __restrict__ row_start, const int* __restrict__ src_sorted,
    const float* __restrict__ s1, const float* __restrict__ d1,
    const __half* __restrict__ h1, const float* __restrict__ b1,
    __half* __restrict__ x2h, int N) {
  __shared__ float wlds[4][64][8];   // [wave][slot][head]
  const int wv = threadIdx.x >> 6;
  const int n = blockIdx.x * 4 + wv;
  if (n >= N) return;
  const int lane = threadIdx.x & 63;
  const int le = lane >> 3, h = lane & 7;     // phase 1
  const int es = lane >> 4, cl = lane & 15;   // phase 2
  const int hh = cl >> 1;
  const int lo = row_start[n], hi = row_start[n + 1];
  const float dv = d1[n * HEADS1 + h];
  float m = -INFINITY, z = 0.f;
  float acc[8] = {0.f, 0.f, 0.f, 0.f, 0.f, 0.f, 0.f, 0.f};
  for (int base = lo; base < hi; base += 64) {
    const int cnt = min(64, hi - base);
    // ---- phase 1: logits once, chunk max, w -> LDS
    float v[8];
#pragma unroll
    for (int r = 0; r < 8; ++r) {
      const int j = (r << 3) + le;
      v[r] = -INFINITY;
      if (j < cnt) v[r] = lrelu(s1[src_sorted[base + j] * HEADS1 + h] + dv);
    }
    float cmax = v[0];
#pragma unroll
    for (int r = 1; r < 8; ++r) cmax = fmaxf(cmax, v[r]);
    cmax = fmaxf(cmax, __shfl_xor(cmax, 8));
    cmax = fmaxf(cmax, __shfl_xor(cmax, 16));
    cmax = fmaxf(cmax, __shfl_xor(cmax, 32));
    const float mnew = fmaxf(m, cmax);
    const float rsc = __expf(m - mnew);   // 0 on first chunk (m=-inf)
    m = mnew;
    z *= rsc;
#pragma unroll
    for (int r = 0; r < 8; ++r) {
      const float w = __expf(v[r] - m);   // 0 for pad slots
      wlds[wv][(r << 3) + le][h] = w;
      z += w;
    }
    // ---- phase 2: rescale acc, wide gather-accumulate
    const float rsc2 = __shfl(rsc, hh);   // lane hh holds head hh's rescale
#pragma unroll
    for (int k = 0; k < 8; ++k) acc[k] *= rsc2;
    for (int i = 0; i < cnt; i += 8) {    // wave-uniform bound
      const int jA = i + es, jB = i + 4 + es;      // <= 63
      const float wA = wlds[wv][jA][hh];           // 0 for pad slots
      const float wB = wlds[wv][jB][hh];
      const int sA = src_sorted[base + min(jA, cnt - 1)];
      const int sB = src_sorted[base + min(jB, cnt - 1)];
      const uint4 fA = ((const uint4*)h1)[(size_t)sA * 16 + cl];
      const uint4 fB = ((const uint4*)h1)[(size_t)sB * 16 + cl];
      const __half2* pA = (const __half2*)&fA;
      const __half2* pB = (const __half2*)&fB;
#pragma unroll
      for (int k = 0; k < 4; ++k) {
        float2 a2 = __half22float2(pA[k]);
        float2 b2v = __half22float2(pB[k]);
        acc[2 * k]     += wA * a2.x + wB * b2v.x;
        acc[2 * k + 1] += wA * a2.y + wB * b2v.y;
      }
    }
  }
  // finalize
  z += __shfl_xor(z, 8); z += __shfl_xor(z, 16); z += __shfl_xor(z, 32);
  const float zsel = __shfl(z, hh);
#pragma unroll
  for (int k = 0; k < 8; ++k) {
    acc[k] += __shfl_xor(acc[k], 16);
    acc[k] += __shfl_xor(acc[k], 32);
  }
  if (es == 0) {
    const float zinv = 1.f / (zsel + 1e-16f);
    __half2 o[4];
#pragma unroll
    for (int k = 0; k < 4; ++k) {
      float ox = acc[2 * k] * zinv + b1[(cl << 3) + 2 * k];
      float oy = acc[2 * k + 1] * zinv + b1[(cl << 3) + 2 * k + 1];
      ox = ox > 0.f ? ox : expm1f(ox);
      oy = oy > 0.f ? oy : expm1f(oy);
      o[k] = __floats2half2_rn(ox, oy);
    }
    ((uint4*)x2h)[(size_t)n * 16 + cl] = *(const uint4*)o;
  }
}

// layer2: one wave per node, 1 head. Phase1: slot=lane. Phase2: es=lane>>3, cl=lane&7.
__global__ __launch_bounds__(256) void layer2_agg(
    const int* __restrict__ row_start, const int* __restrict__ src_sorted,
    const float* __restrict__ s2, const float* __restrict__ d2,
    const __half* __restrict__ h2, const float* __restrict__ b2,
    float* __restrict__ out, int N) {
  const int n = blockIdx.x * 4 + (threadIdx.x >> 6);
  if (n >= N) return;
  const int lane = threadIdx.x & 63;
  const int es = lane >> 3, cl = lane & 7;
  const int lo = row_start[n], hi = row_start[n + 1];
  const float dv = d2[n];
  float m = -INFINITY, z = 0.f;
  float acc[8] = {0.f, 0.f, 0.f, 0.f, 0.f, 0.f, 0.f, 0.f};
  for (int base = lo; base < hi; base += 64) {
    const int cnt = min(64, hi - base);
    float v = -INFINITY;
    if (lane < cnt) v = lrelu(s2[src_sorted[base + lane]] + dv);
    float cmax = v;
#pragma unroll
    for (int off = 1; off < 64; off <<= 1) cmax = fmaxf(cmax, __shfl_xor(cmax, off));
    const float mnew = fmaxf(m, cmax);
    const float rsc = __expf(m - mnew);
    m = mnew;
    const float w = __expf(v - m);        // 0 for pad slots
    z = z * rsc + w;
#pragma unroll
    for (int k = 0; k < 8; ++k) acc[k] *= rsc;
    for (int i = 0; i < cnt; i += 16) {   // wave-uniform
      const int jA = i + es, jB = i + 8 + es;      // <= 63
      const float wA = __shfl(w, jA);
      const float wB = __shfl(w, jB);
      const int sA = src_sorted[base + min(jA, cnt - 1)];
      const int sB = src_sorted[base + min(jB, cnt - 1)];
      const uint4 fA = ((const uint4*)h2)[(size_t)sA * 8 + cl];
      const uint4 fB = ((const uint4*)h2)[(size_t)sB * 8 + cl];
      const __half2* pA = (const __half2*)&fA;
      const __half2* pB = (const __half2*)&fB;
#pragma unroll
      for (int k = 0; k < 4; ++k) {
        float2 a2 = __half22float2(pA[k]);
        float2 b2v = __half22float2(pB[k]);
        acc[2 * k]     += wA * a2.x + wB * b2v.x;
        acc[2 * k + 1] += wA * a2.y + wB * b2v.y;
      }
    }
  }
#pragma unroll
  for (int off = 1; off < 64; off <<= 1) z += __shfl_xor(z, off);
#pragma unroll
  for (int k = 0; k < 8; ++k) {
    acc[k] += __shfl_xor(acc[k], 8);
    acc[k] += __shfl_xor(acc[k], 16);
    acc[k] += __shfl_xor(acc[k], 32);
  }
  if (es == 0) {
    const float zinv = 1.f / (z + 1e-16f);
    float4 o0, o1;
    o0.x = acc[0] * zinv + b2[(cl << 3) + 0];
    o0.y = acc[1] * zinv + b2[(cl << 3) + 1];
    o0.z = acc[2] * zinv + b2[(cl << 3) + 2];
    o0.w = acc[3] * zinv + b2[(cl << 3) + 3];
    o1.x = acc[4] * zinv + b2[(cl << 3) + 4];
    o1.y = acc[5] * zinv + b2[(cl << 3) + 5];
    o1.z = acc[6] * zinv + b2[(cl << 3) + 6];
    o1.w = acc[7] * zinv + b2[(cl << 3) + 7];
    float4* po = (float4*)&out[(size_t)n * C2 + (cl << 3)];
    po[0] = o0;
    po[1] = o1;
  }
}

extern "C" void kernel_launch(void* const* d_in, const int* in_sizes, int n_in,
                              void* d_out, int out_size, void* d_ws, size_t ws_size,
                              hipStream_t stream) {
  const float* x      = (const float*)d_in[0];
  const int*   ei     = (const int*)d_in[1];
  const float* W1     = (const float*)d_in[2];
  const float* a_src1 = (const float*)d_in[3];
  const float* a_dst1 = (const float*)d_in[4];
  const float* b1     = (const float*)d_in[5];
  const float* W2     = (const float*)d_in[6];
  const float* a_src2 = (const float*)d_in[7];
  const float* a_dst2 = (const float*)d_in[8];
  const float* b2     = (const float*)d_in[9];
  float* out = (float*)d_out;

  const int N = in_sizes[0] / INCH;
  const int E = in_sizes[1] / 2;
  const int* src = ei;
  const int* dst = ei + E;

  // Workspace layout (~46 MB; >=71 MB proven available)
  float* ws = (float*)d_ws;
  size_t o = 0;
  __half* xh  = (__half*)(ws + o); o += (size_t)N * C1 / 2;   // x fp16
  __half* h1  = (__half*)(ws + o); o += (size_t)N * C1 / 2;   // layer-1 features fp16
  __half* x2h = (__half*)(ws + o); o += (size_t)N * C1 / 2;   // layer-2 input fp16
  float*  s1  = ws + o;            o += (size_t)N * HEADS1;
  float*  d1  = ws + o;            o += (size_t)N * HEADS1;
  __half* W1t = (__half*)(ws + o); o += 128 * 128 / 2;
  __half* W2t = (__half*)(ws + o); o += 64 * 128 / 2;
  int* deg        = (int*)(ws + o); o += N;
  int* cursor     = (int*)(ws + o); o += N;
  int* row_start  = (int*)(ws + o); o += N + 1;
  int* partial    = (int*)(ws + o); o += SB;
  int* src_sorted = (int*)(ws + o); o += E;
  // layer-2 aliases into h1's region (h1 dead after layer1_agg)
  __half* h2 = h1;                                   // N*64 halves
  float*  s2 = (float*)h1 + (size_t)N * 32;          // N floats
  float*  d2 = s2 + N;                               // N floats

  const int EB = (E + 255) / 256;
  const int NB64 = (N + 63) / 64;
  const int total8 = N * C1 / 8;
  const int cvtB = (total8 + 255) / 256;
  const int tB = (128 * 128 + 64 * 128 + 255) / 256;
  const int histB = EB;

  hipMemsetAsync(deg, 0, (size_t)N * 4, stream);
  hipMemsetAsync(cursor, 0, (size_t)N * 4, stream);

  prep_kernel<<<cvtB + tB + histB, 256, 0, stream>>>(x, xh, W1, W1t, W2, W2t, dst, deg,
                                                     cvtB, tB, total8, E);
  scan1_kernel<<<SB, SB, 0, stream>>>(deg, partial, N);
  scan3_kernel<<<SB, SB, 0, stream>>>(deg, partial, row_start, N);
  fill_kernel<<<EB, 256, 0, stream>>>(src, dst, row_start, cursor, src_sorted, E);

  // Layer 1
  gemm1_mfma<<<NB64, 256, 0, stream>>>(xh, W1t, a_src1, a_dst1, h1, s1, d1, N);
  layer1_agg<<<(N + 3) / 4, 256, 0, stream>>>(row_start, src_sorted, s1, d1, h1, b1, x2h, N);

  // Layer 2
  gemm2_mfma<<<NB64, 256, 0, stream>>>(x2h, W2t, a_src2, a_dst2, h2, s2, d2, N);
  layer2_agg<<<(N + 3) / 4, 256, 0, stream>>>(row_start, src_sorted, s2, d2, h2, b2, out, N);
}

// Round 9
// 213.438 us; speedup vs baseline: 1.1868x; 1.0473x over previous
//
#include <hip/hip_runtime.h>
#include <hip/hip_fp16.h>

#define INCH   128
#define HEADS1 8
#define HID1   16
#define C1     128   // HEADS1*HID1
#define C2     64
#define NEG_SLOPE 0.2f
#define SB     256   // scan blocks / threads

using f16x8 = __attribute__((ext_vector_type(8))) _Float16;
using f32x4 = __attribute__((ext_vector_type(4))) float;

__device__ __forceinline__ float lrelu(float v) { return v >= 0.f ? v : NEG_SLOPE * v; }
// byte-offset swizzle within a 256B LDS row (rows are 128 fp16)
__device__ __forceinline__ int swzA(int row, int byteInRow) {
  return (row << 8) | (byteInRow ^ ((row & 15) << 4));
}

// ---------------- fused prep: x->fp16, W1/W2 transpose->fp16, dst histogram ----------------

__global__ void prep_kernel(const float* __restrict__ x, __half* __restrict__ xh,
                            const float* __restrict__ W1, __half* __restrict__ W1t,
                            const float* __restrict__ W2, __half* __restrict__ W2t,
                            const int* __restrict__ dst, int* __restrict__ deg,
                            int cvtB, int tB, int total8, int E) {
  const int b = blockIdx.x, t = threadIdx.x;
  if (b < cvtB) {
    int i = b * 256 + t;
    if (i >= total8) return;
    const float4* p = (const float4*)x + (size_t)i * 2;
    float4 v0 = p[0], v1 = p[1];
    __half2 ha = __floats2half2_rn(v0.x, v0.y);
    __half2 hb = __floats2half2_rn(v0.z, v0.w);
    __half2 hc = __floats2half2_rn(v1.x, v1.y);
    __half2 hd = __floats2half2_rn(v1.z, v1.w);
    uint4 w = { *(unsigned*)&ha, *(unsigned*)&hb, *(unsigned*)&hc, *(unsigned*)&hd };
    ((uint4*)xh)[i] = w;
  } else if (b < cvtB + tB) {
    int id = (b - cvtB) * 256 + t;
    if (id < 128 * 128) {
      int col = id >> 7, k = id & 127;
      W1t[id] = __float2half(W1[k * 128 + col]);
    } else if (id < 128 * 128 + 64 * 128) {
      int idx = id - 128 * 128;
      int col = idx >> 7, k = idx & 127;
      W2t[idx] = __float2half(W2[k * 64 + col]);
    }
  } else {
    int e = (b - cvtB - tB) * 256 + t;
    if (e < E) atomicAdd(&deg[dst[e]], 1);
  }
}

// ---------------- CSR build (by destination) ----------------

__global__ void scan1_kernel(const int* __restrict__ deg, int* __restrict__ partial, int N) {
  __shared__ int sh[SB];
  const int b = blockIdx.x, t = threadIdx.x;
  const int chunk = (N + SB - 1) / SB;
  const int lo = b * chunk, hi = min(lo + chunk, N);
  int s = 0;
  for (int i = lo + t; i < hi; i += SB) s += deg[i];
  sh[t] = s;
  __syncthreads();
  for (int off = SB / 2; off; off >>= 1) {
    if (t < off) sh[t] += sh[t + off];
    __syncthreads();
  }
  if (t == 0) partial[b] = sh[0];
}

// stage 2+3 fused: each block locally scans the 256 partials, then scans its chunk.
__global__ void scan3_kernel(const int* __restrict__ deg, const int* __restrict__ partial,
                             int* __restrict__ row_start, int N) {
  __shared__ int pref[SB];
  __shared__ int sh[SB];
  const int b = blockIdx.x, t = threadIdx.x;
  int pv = partial[t];
  pref[t] = pv;
  __syncthreads();
  for (int off = 1; off < SB; off <<= 1) {
    int u = (t >= off) ? pref[t - off] : 0;
    __syncthreads();
    pref[t] += u;
    __syncthreads();
  }
  const int chunk = (N + SB - 1) / SB;
  const int lo = b * chunk, hi = min(lo + chunk, N);
  int run = (b == 0) ? 0 : pref[b - 1];
  for (int base = lo; base < hi; base += SB) {
    int i = base + t;
    int v = (i < hi) ? deg[i] : 0;
    sh[t] = v;
    __syncthreads();
    for (int off = 1; off < SB; off <<= 1) {
      int u = (t >= off) ? sh[t - off] : 0;
      __syncthreads();
      sh[t] += u;
      __syncthreads();
    }
    if (i < hi) row_start[i] = run + sh[t] - v;
    run += sh[SB - 1];
    __syncthreads();
  }
  if (b == SB - 1 && t == 0) row_start[N] = run;
}

__global__ void fill_kernel(const int* __restrict__ src, const int* __restrict__ dst,
                            const int* __restrict__ row_start, int* __restrict__ cursor,
                            int* __restrict__ src_sorted, int E) {
  int e = blockIdx.x * blockDim.x + threadIdx.x;
  if (e >= E) return;
  int d = dst[e];
  int slot = row_start[d] + atomicAdd(&cursor[d], 1);
  src_sorted[slot] = src[e];
}

// ---------------- MFMA GEMMs ----------------
// gemm1: [M x 128] x [128 x 128]; 256 thr = 4 waves; block does 64 rows x 128 cols.
__global__ __launch_bounds__(256) void gemm1_mfma(
    const __half* __restrict__ xh, const __half* __restrict__ W1t,
    const float* __restrict__ a_src, const float* __restrict__ a_dst,
    __half* __restrict__ h1, float* __restrict__ s1, float* __restrict__ d1, int M) {
  __shared__ unsigned char As[16384];   // 64 x 128 fp16, swizzled
  __shared__ unsigned char Bs[32768];   // 128 x 128 fp16 (col-major W1), swizzled
  const int t = threadIdx.x;
  const int m0 = blockIdx.x * 64;
  for (int c = t; c < 1024; c += 256) {
    int row = c >> 4, seg = c & 15;
    int gr = m0 + row;
    uint4 v = make_uint4(0, 0, 0, 0);
    if (gr < M) v = ((const uint4*)xh)[(size_t)gr * 16 + seg];
    *(uint4*)(As + swzA(row, seg << 4)) = v;
  }
  for (int c = t; c < 2048; c += 256) {
    int row = c >> 4, seg = c & 15;
    uint4 v = ((const uint4*)W1t)[(row << 4) + seg];
    *(uint4*)(Bs + swzA(row, seg << 4)) = v;
  }
  __syncthreads();
  const int l = t & 63, wid = t >> 6;
  const int c16 = l & 15;
  const int kOff = (l >> 4) << 4;
  const int rA = (wid << 4) | c16;
  f16x8 a[4];
#pragma unroll
  for (int kb = 0; kb < 4; ++kb)
    a[kb] = *(const f16x8*)(As + swzA(rA, (kb << 6) + kOff));
#pragma unroll
  for (int ct = 0; ct < 8; ++ct) {        // ct == head (HID1 == 16)
    const int rB = (ct << 4) | c16;
    f32x4 acc = {0.f, 0.f, 0.f, 0.f};
#pragma unroll
    for (int kb = 0; kb < 4; ++kb) {
      f16x8 b = *(const f16x8*)(Bs + swzA(rB, (kb << 6) + kOff));
      acc = __builtin_amdgcn_mfma_f32_16x16x32_f16(a[kb], b, acc, 0, 0, 0);
    }
    const int colg = (ct << 4) + c16;
    const float asv = a_src[colg], adv = a_dst[colg];
#pragma unroll
    for (int i = 0; i < 4; ++i) {
      const int n = m0 + (wid << 4) + ((l >> 4) << 2) + i;
      float v = acc[i];
      float sv = v * asv, dv = v * adv;
      sv += __shfl_xor(sv, 1); sv += __shfl_xor(sv, 2);
      sv += __shfl_xor(sv, 4); sv += __shfl_xor(sv, 8);
      dv += __shfl_xor(dv, 1); dv += __shfl_xor(dv, 2);
      dv += __shfl_xor(dv, 4); dv += __shfl_xor(dv, 8);
      if (n < M) {
        h1[(size_t)n * C1 + colg] = __float2half(v);
        if (c16 == 0) { s1[n * HEADS1 + ct] = sv; d1[n * HEADS1 + ct] = dv; }
      }
    }
  }
}

// gemm2: [M x 128] x [128 x 64]
__global__ __launch_bounds__(256) void gemm2_mfma(
    const __half* __restrict__ x2h, const __half* __restrict__ W2t,
    const float* __restrict__ a_src, const float* __restrict__ a_dst,
    __half* __restrict__ h2, float* __restrict__ s2, float* __restrict__ d2, int M) {
  __shared__ unsigned char As[16384];   // 64 x 128 fp16
  __shared__ unsigned char Bs[16384];   // 64 x 128 fp16 (col-major W2)
  const int t = threadIdx.x;
  const int m0 = blockIdx.x * 64;
  for (int c = t; c < 1024; c += 256) {
    int row = c >> 4, seg = c & 15;
    int gr = m0 + row;
    uint4 v = make_uint4(0, 0, 0, 0);
    if (gr < M) v = ((const uint4*)x2h)[(size_t)gr * 16 + seg];
    *(uint4*)(As + swzA(row, seg << 4)) = v;
  }
  for (int c = t; c < 1024; c += 256) {
    int row = c >> 4, seg = c & 15;
    uint4 v = ((const uint4*)W2t)[(row << 4) + seg];
    *(uint4*)(Bs + swzA(row, seg << 4)) = v;
  }
  __syncthreads();
  const int l = t & 63, wid = t >> 6;
  const int c16 = l & 15;
  const int kOff = (l >> 4) << 4;
  const int rA = (wid << 4) | c16;
  f16x8 a[4];
#pragma unroll
  for (int kb = 0; kb < 4; ++kb)
    a[kb] = *(const f16x8*)(As + swzA(rA, (kb << 6) + kOff));
  float svp[4] = {0.f, 0.f, 0.f, 0.f};
  float dvp[4] = {0.f, 0.f, 0.f, 0.f};
#pragma unroll
  for (int ct = 0; ct < 4; ++ct) {
    const int rB = (ct << 4) | c16;
    f32x4 acc = {0.f, 0.f, 0.f, 0.f};
#pragma unroll
    for (int kb = 0; kb < 4; ++kb) {
      f16x8 b = *(const f16x8*)(Bs + swzA(rB, (kb << 6) + kOff));
      acc = __builtin_amdgcn_mfma_f32_16x16x32_f16(a[kb], b, acc, 0, 0, 0);
    }
    const int colg = (ct << 4) + c16;
    const float asv = a_src[colg], adv = a_dst[colg];
#pragma unroll
    for (int i = 0; i < 4; ++i) {
      const int n = m0 + (wid << 4) + ((l >> 4) << 2) + i;
      float v = acc[i];
      svp[i] += v * asv;
      dvp[i] += v * adv;
      if (n < M) h2[(size_t)n * C2 + colg] = __float2half(v);
    }
  }
#pragma unroll
  for (int i = 0; i < 4; ++i) {
    float sv = svp[i], dv = dvp[i];
    sv += __shfl_xor(sv, 1); sv += __shfl_xor(sv, 2);
    sv += __shfl_xor(sv, 4); sv += __shfl_xor(sv, 8);
    dv += __shfl_xor(dv, 1); dv += __shfl_xor(dv, 2);
    dv += __shfl_xor(dv, 4); dv += __shfl_xor(dv, 8);
    const int n = m0 + (wid << 4) + ((l >> 4) << 2) + i;
    if (c16 == 0 && n < M) { s2[n] = sv; d2[n] = dv; }
  }
}

// ---------------- Fused softmax + wide aggregation (no max pass) ----------------
// Softmax is shift-invariant; logits here are lrelu(s+d) with |.| <~ 8 for this
// model's 1/sqrt(fan_in)-scaled weights, so exp() is fp32-safe without the
// numerically-stable max subtraction. Single streaming pass per node.
// layer1: one wave per node; chunks of 64 edges.
//   Phase 1: le=lane>>3 (edge slot j=r*8+le), h=lane&7: w=exp(lrelu(s1+d)) -> LDS, z+=w.
//   Phase 2: es=lane>>4 (4 edge slots), cl=lane&15 (16B of the 256B h1 row).
__global__ __launch_bounds__(256) void layer1_agg(
    const int* __restrict__ row_start, const int* __restrict__ src_sorted,
    const float* __restrict__ s1, const float* __restrict__ d1,
    const __half* __restrict__ h1, const float* __restrict__ b1,
    __half* __restrict__ x2h, int N) {
  __shared__ float wlds[4][64][8];   // [wave][slot][head]
  const int wv = threadIdx.x >> 6;
  const int n = blockIdx.x * 4 + wv;
  if (n >= N) return;
  const int lane = threadIdx.x & 63;
  const int le = lane >> 3, h = lane & 7;     // phase 1
  const int es = lane >> 4, cl = lane & 15;   // phase 2
  const int hh = cl >> 1;
  const int lo = row_start[n], hi = row_start[n + 1];
  const float dv = d1[n * HEADS1 + h];
  float z = 0.f;
  float acc[8] = {0.f, 0.f, 0.f, 0.f, 0.f, 0.f, 0.f, 0.f};
  for (int base = lo; base < hi; base += 64) {
    const int cnt = min(64, hi - base);
    // ---- phase 1: w = exp(logit) straight, -> LDS
#pragma unroll
    for (int r = 0; r < 8; ++r) {
      const int j = (r << 3) + le;
      float w = 0.f;
      if (j < cnt) w = __expf(lrelu(s1[src_sorted[base + j] * HEADS1 + h] + dv));
      wlds[wv][j][h] = w;
      z += w;
    }
    // ---- phase 2: wide gather-accumulate
    for (int i = 0; i < cnt; i += 8) {    // wave-uniform bound
      const int jA = i + es, jB = i + 4 + es;      // <= 63
      const float wA = wlds[wv][jA][hh];           // 0 for pad slots
      const float wB = wlds[wv][jB][hh];
      const int sA = src_sorted[base + min(jA, cnt - 1)];
      const int sB = src_sorted[base + min(jB, cnt - 1)];
      const uint4 fA = ((const uint4*)h1)[(size_t)sA * 16 + cl];
      const uint4 fB = ((const uint4*)h1)[(size_t)sB * 16 + cl];
      const __half2* pA = (const __half2*)&fA;
      const __half2* pB = (const __half2*)&fB;
#pragma unroll
      for (int k = 0; k < 4; ++k) {
        float2 a2 = __half22float2(pA[k]);
        float2 b2v = __half22float2(pB[k]);
        acc[2 * k]     += wA * a2.x + wB * b2v.x;
        acc[2 * k + 1] += wA * a2.y + wB * b2v.y;
      }
    }
  }
  // finalize: z currently per (le,h) partial; reduce over le (lanes with same h)
  z += __shfl_xor(z, 8); z += __shfl_xor(z, 16); z += __shfl_xor(z, 32);
  const float zsel = __shfl(z, hh);   // lane hh holds head hh's total
#pragma unroll
  for (int k = 0; k < 8; ++k) {
    acc[k] += __shfl_xor(acc[k], 16);
    acc[k] += __shfl_xor(acc[k], 32);
  }
  if (es == 0) {
    const float zinv = 1.f / (zsel + 1e-16f);
    __half2 o[4];
#pragma unroll
    for (int k = 0; k < 4; ++k) {
      float ox = acc[2 * k] * zinv + b1[(cl << 3) + 2 * k];
      float oy = acc[2 * k + 1] * zinv + b1[(cl << 3) + 2 * k + 1];
      ox = ox > 0.f ? ox : expm1f(ox);
      oy = oy > 0.f ? oy : expm1f(oy);
      o[k] = __floats2half2_rn(ox, oy);
    }
    ((uint4*)x2h)[(size_t)n * 16 + cl] = *(const uint4*)o;
  }
}

// layer2: one wave per node, 1 head. Phase1: slot=lane (w in register, shared by
// shuffle). Phase2: es=lane>>3, cl=lane&7.
__global__ __launch_bounds__(256) void layer2_agg(
    const int* __restrict__ row_start, const int* __restrict__ src_sorted,
    const float* __restrict__ s2, const float* __restrict__ d2,
    const __half* __restrict__ h2, const float* __restrict__ b2,
    float* __restrict__ out, int N) {
  const int n = blockIdx.x * 4 + (threadIdx.x >> 6);
  if (n >= N) return;
  const int lane = threadIdx.x & 63;
  const int es = lane >> 3, cl = lane & 7;
  const int lo = row_start[n], hi = row_start[n + 1];
  const float dv = d2[n];
  float z = 0.f;
  float acc[8] = {0.f, 0.f, 0.f, 0.f, 0.f, 0.f, 0.f, 0.f};
  for (int base = lo; base < hi; base += 64) {
    const int cnt = min(64, hi - base);
    float w = 0.f;
    if (lane < cnt) w = __expf(lrelu(s2[src_sorted[base + lane]] + dv));
    z += w;
    for (int i = 0; i < cnt; i += 16) {   // wave-uniform
      const int jA = i + es, jB = i + 8 + es;      // <= 63
      const float wA = __shfl(w, jA);
      const float wB = __shfl(w, jB);
      const int sA = src_sorted[base + min(jA, cnt - 1)];
      const int sB = src_sorted[base + min(jB, cnt - 1)];
      const uint4 fA = ((const uint4*)h2)[(size_t)sA * 8 + cl];
      const uint4 fB = ((const uint4*)h2)[(size_t)sB * 8 + cl];
      const __half2* pA = (const __half2*)&fA;
      const __half2* pB = (const __half2*)&fB;
#pragma unroll
      for (int k = 0; k < 4; ++k) {
        float2 a2 = __half22float2(pA[k]);
        float2 b2v = __half22float2(pB[k]);
        acc[2 * k]     += wA * a2.x + wB * b2v.x;
        acc[2 * k + 1] += wA * a2.y + wB * b2v.y;
      }
    }
  }
#pragma unroll
  for (int off = 1; off < 64; off <<= 1) z += __shfl_xor(z, off);
#pragma unroll
  for (int k = 0; k < 8; ++k) {
    acc[k] += __shfl_xor(acc[k], 8);
    acc[k] += __shfl_xor(acc[k], 16);
    acc[k] += __shfl_xor(acc[k], 32);
  }
  if (es == 0) {
    const float zinv = 1.f / (z + 1e-16f);
    float4 o0, o1;
    o0.x = acc[0] * zinv + b2[(cl << 3) + 0];
    o0.y = acc[1] * zinv + b2[(cl << 3) + 1];
    o0.z = acc[2] * zinv + b2[(cl << 3) + 2];
    o0.w = acc[3] * zinv + b2[(cl << 3) + 3];
    o1.x = acc[4] * zinv + b2[(cl << 3) + 4];
    o1.y = acc[5] * zinv + b2[(cl << 3) + 5];
    o1.z = acc[6] * zinv + b2[(cl << 3) + 6];
    o1.w = acc[7] * zinv + b2[(cl << 3) + 7];
    float4* po = (float4*)&out[(size_t)n * C2 + (cl << 3)];
    po[0] = o0;
    po[1] = o1;
  }
}

extern "C" void kernel_launch(void* const* d_in, const int* in_sizes, int n_in,
                              void* d_out, int out_size, void* d_ws, size_t ws_size,
                              hipStream_t stream) {
  const float* x      = (const float*)d_in[0];
  const int*   ei     = (const int*)d_in[1];
  const float* W1     = (const float*)d_in[2];
  const float* a_src1 = (const float*)d_in[3];
  const float* a_dst1 = (const float*)d_in[4];
  const float* b1     = (const float*)d_in[5];
  const float* W2     = (const float*)d_in[6];
  const float* a_src2 = (const float*)d_in[7];
  const float* a_dst2 = (const float*)d_in[8];
  const float* b2     = (const float*)d_in[9];
  float* out = (float*)d_out;

  const int N = in_sizes[0] / INCH;
  const int E = in_sizes[1] / 2;
  const int* src = ei;
  const int* dst = ei + E;

  // Workspace layout (~46 MB; >=71 MB proven available)
  float* ws = (float*)d_ws;
  size_t o = 0;
  __half* xh  = (__half*)(ws + o); o += (size_t)N * C1 / 2;   // x fp16
  __half* h1  = (__half*)(ws + o); o += (size_t)N * C1 / 2;   // layer-1 features fp16
  __half* x2h = (__half*)(ws + o); o += (size_t)N * C1 / 2;   // layer-2 input fp16
  float*  s1  = ws + o;            o += (size_t)N * HEADS1;
  float*  d1  = ws + o;            o += (size_t)N * HEADS1;
  __half* W1t = (__half*)(ws + o); o += 128 * 128 / 2;
  __half* W2t = (__half*)(ws + o); o += 64 * 128 / 2;
  int* deg        = (int*)(ws + o); o += N;
  int* cursor     = (int*)(ws + o); o += N;
  int* row_start  = (int*)(ws + o); o += N + 1;
  int* partial    = (int*)(ws + o); o += SB;
  int* src_sorted = (int*)(ws + o); o += E;
  // layer-2 aliases into h1's region (h1 dead after layer1_agg)
  __half* h2 = h1;                                   // N*64 halves
  float*  s2 = (float*)h1 + (size_t)N * 32;          // N floats
  float*  d2 = s2 + N;                               // N floats

  const int EB = (E + 255) / 256;
  const int NB64 = (N + 63) / 64;
  const int total8 = N * C1 / 8;
  const int cvtB = (total8 + 255) / 256;
  const int tB = (128 * 128 + 64 * 128 + 255) / 256;
  const int histB = EB;

  hipMemsetAsync(deg, 0, (size_t)N * 4, stream);
  hipMemsetAsync(cursor, 0, (size_t)N * 4, stream);

  prep_kernel<<<cvtB + tB + histB, 256, 0, stream>>>(x, xh, W1, W1t, W2, W2t, dst, deg,
                                                     cvtB, tB, total8, E);
  scan1_kernel<<<SB, SB, 0, stream>>>(deg, partial, N);
  scan3_kernel<<<SB, SB, 0, stream>>>(deg, partial, row_start, N);
  fill_kernel<<<EB, 256, 0, stream>>>(src, dst, row_start, cursor, src_sorted, E);

  // Layer 1
  gemm1_mfma<<<NB64, 256, 0, stream>>>(xh, W1t, a_src1, a_dst1, h1, s1, d1, N);
  layer1_agg<<<(N + 3) / 4, 256, 0, stream>>>(row_start, src_sorted, s1, d1, h1, b1, x2h, N);

  // Layer 2
  gemm2_mfma<<<NB64, 256, 0, stream>>>(x2h, W2t, a_src2, a_dst2, h2, s2, d2, N);
  layer2_agg<<<(N + 3) / 4, 256, 0, stream>>>(row_start, src_sorted, s2, d2, h2, b2, out, N);
}